// Round 5
// baseline (171.564 us; speedup 1.0000x reference)
//
#include <hip/hip_runtime.h>

typedef unsigned long long ull;

#define N_PTS   1000000
#define DM      128
#define DP      64
#define RNB     32
#define ENT     32
#define EFS     64
#define KOUT    10
#define NITERS  8
#define NTH     512
#define NWAVE   (NTH / 64)
#define HASHCAP 32768
#define MAXNEW  2112
#define BIGF    1e30f
#define PADKEY  0xFFFFFFFFFFFFFFFFull

__device__ __forceinline__ unsigned fkey_enc(float d) {
  unsigned b = __float_as_uint(d);
  return (b & 0x80000000u) ? ~b : (b | 0x80000000u);
}

// Distance in principal subspace (first 64 dims). Fixed accumulation order;
// BIT-IDENTICAL to rounds 0-4 (absmax was 0.0). Do not perturb.
__device__ __forceinline__ float dist_p(const float* __restrict__ storage,
                                        const float* qf, float qn, int id) {
  int c = id < 0 ? 0 : (id > N_PTS - 1 ? N_PTS - 1 : id);
  const float4* row = (const float4*)(storage + (size_t)c * DM);
  float sq = 0.f, dt = 0.f;
#pragma unroll
  for (int j = 0; j < DP / 4; ++j) {
    float4 s = row[j];
    sq = fmaf(s.x, s.x, sq); sq = fmaf(s.y, s.y, sq);
    sq = fmaf(s.z, s.z, sq); sq = fmaf(s.w, s.w, sq);
    dt = fmaf(s.x, qf[4*j+0], dt); dt = fmaf(s.y, qf[4*j+1], dt);
    dt = fmaf(s.z, qf[4*j+2], dt); dt = fmaf(s.w, qf[4*j+3], dt);
  }
  float d = sq - 2.f * dt + qn;
  return (id >= N_PTS) ? BIGF : d;
}

__device__ __forceinline__ bool visit_claim(int* htab, int id) {
  unsigned h = ((unsigned)id * 2654435761u) & (HASHCAP - 1);
  while (true) {
    int cur = htab[h];
    if (cur == id) return false;
    if (cur == -1) {
      int old = atomicCAS(&htab[h], -1, id);
      if (old == -1) return true;
      if (old == id) return false;
    }
    h = (h + 1) & (HASHCAP - 1);
  }
}

__device__ __forceinline__ ull wsort64(ull key, int lane) {
#pragma unroll
  for (int k = 2; k <= 64; k <<= 1) {
#pragma unroll
    for (int j = k >> 1; j > 0; j >>= 1) {
      ull other = __shfl_xor(key, j);
      bool up = ((lane & k) == 0);
      bool lower = ((lane & j) == 0);
      ull mn = key < other ? key : other;
      ull mx = key < other ? other : key;
      key = (up == lower) ? mn : mx;
    }
  }
  return key;
}

__device__ __forceinline__ ull wbmerge64(ull key, int lane) {
#pragma unroll
  for (int j = 32; j > 0; j >>= 1) {
    ull other = __shfl_xor(key, j);
    bool lower = ((lane & j) == 0);
    ull mn = key < other ? key : other;
    ull mx = key < other ? other : key;
    key = lower ? mn : mx;
  }
  return key;
}

__device__ __forceinline__ ull wmerge(ull a, ull b, int lane) {
  ull brev = __shfl_xor(b, 63);
  ull c = a < brev ? a : brev;
  return wbmerge64(c, lane);
}

// ---------------- shared device subroutines ----------------

__device__ __forceinline__ void compute_qf(const float* query, const float* VT,
                                           float* qloc, float* qf, float* qn_s,
                                           int b, int tid) {
  if (tid < DM) qloc[tid] = query[(size_t)b * DM + tid];
  __syncthreads();
  if (tid < DM) {
    const float* vrow = VT + (size_t)tid * DM;
    float acc = 0.f;
#pragma unroll 8
    for (int d = 0; d < DM; ++d) acc = fmaf(qloc[d], vrow[d], acc);
    qf[tid] = acc;
  }
  __syncthreads();
  if (tid == 0) {
    float acc = 0.f;
    for (int d = 0; d < DP; ++d) acc = fmaf(qf[d], qf[d], acc);
    *qn_s = acc;
  }
  __syncthreads();
}

__device__ __forceinline__ void final_topk(const float* storage, const float* qf,
                                           const int* beam_id, float* dfull,
                                           float* out, int b, int B,
                                           int lane, int wid) {
  if (wid == 0) {
    int id = beam_id[lane];
    int c = id < 0 ? 0 : (id > N_PTS - 1 ? N_PTS - 1 : id);
    const float4* row = (const float4*)(storage + (size_t)c * DM);
    float acc = 0.f;
#pragma unroll
    for (int j = 0; j < DM / 4; ++j) {
      float4 s = row[j];
      float dx = s.x - qf[4*j+0]; acc = fmaf(dx, dx, acc);
      dx = s.y - qf[4*j+1]; acc = fmaf(dx, dx, acc);
      dx = s.z - qf[4*j+2]; acc = fmaf(dx, dx, acc);
      dx = s.w - qf[4*j+3]; acc = fmaf(dx, dx, acc);
    }
    float dv = (id >= N_PTS) ? BIGF : acc;
    dfull[lane] = dv;
    ull fk = ((ull)fkey_enc(dv) << 32) | (unsigned)lane;
    fk = wsort64(fk, lane);
    if (lane < KOUT) {
      int pos = (int)(fk & 0xFFFFFFFFull);
      out[(size_t)b * KOUT + lane] = (float)beam_id[pos];
      out[(size_t)B * KOUT + (size_t)b * KOUT + lane] = dfull[pos];
    }
  }
}

// ---------------- paired kernel (2 blocks per query) ----------------

__global__ __launch_bounds__(NTH) void search_pair(
    const float* __restrict__ query, const float* __restrict__ VT,
    const float* __restrict__ storage, const int* __restrict__ neighbors,
    const int* __restrict__ entry_ids, float* __restrict__ out,
    ull* __restrict__ pay,   // [pair][iter][parity][64]
    int* __restrict__ flags, // [pair][iter][parity]
    int B)
{
  __shared__ int   htab[HASHCAP];        // 128 KB
  __shared__ ull   newkeys[MAXNEW];
  __shared__ ull   wavetop[NWAVE][64];
  __shared__ ull   beamkey[EFS];
  __shared__ int   beam_id[EFS];
  __shared__ float qf[DM];
  __shared__ float qloc[DM];
  __shared__ float qn_s;
  __shared__ int   nc, stop;
  __shared__ float dfull[EFS];

  const int pair   = blockIdx.x >> 1;
  const int parity = blockIdx.x & 1;
  const int b      = pair;
  const int tid    = threadIdx.x;
  const int lane   = tid & 63;
  const int wid    = tid >> 6;

  const ull FILLKEY = ((ull)fkey_enc(BIGF) << 32) | (unsigned)N_PTS;

  for (int i = tid; i < HASHCAP; i += NTH) htab[i] = -1;

  compute_qf(query, VT, qloc, qf, &qn_s, b, tid);
  const float qn = qn_s;

  // entry stage: identical in both blocks of the pair
  if (wid == 0) {
    ull ek = PADKEY;
    if (lane < ENT) {
      int id = entry_ids[lane];
      if (visit_claim(htab, id)) {
        float d = dist_p(storage, qf, qn, id);
        ek = ((ull)fkey_enc(d) << 32) | (unsigned)id;
      }
    }
    ek = wsort64(ek, lane);
    if (ek == PADKEY) ek = FILLKEY;
    beamkey[lane] = ek;
    beam_id[lane] = (int)(ek & 0xFFFFFFFFull);
  }
  __syncthreads();

  for (int it = 0; it < NITERS; ++it) {
    ull kmax = beamkey[EFS - 1];
    if (tid == 0) nc = 0;
    __syncthreads();

    // fused propose + claim (all ids) + evaluate (own parity only)
    for (int ci = tid; ci < EFS * RNB; ci += NTH) {
      int e = ci >> 5;
      int r = ci & 31;
      int bid = beam_id[e];
      if (bid >= N_PTS) continue;
      int cid = neighbors[(size_t)bid * RNB + r];
      if (!visit_claim(htab, cid)) continue;
      if ((cid & 1) != parity) continue;        // partner evaluates this one
      float d = dist_p(storage, qf, qn, cid);
      ull key = ((ull)fkey_enc(d) << 32) | (unsigned)cid;
      if (key < kmax) {
        int p = atomicAdd(&nc, 1);
        newkeys[p] = key;
      }
    }
    __syncthreads();

    int cnt = nc;

    // per-wave top-64 (registers + shuffles)
    ull tk = PADKEY;
    int nchunks = (cnt + 63) >> 6;
    for (int c = wid; c < nchunks; c += NWAVE) {
      int idx = (c << 6) + lane;
      ull v = (idx < cnt) ? newkeys[idx] : PADKEY;
      v = wsort64(v, lane);
      tk = wmerge(tk, v, lane);
    }
    wavetop[wid][lane] = tk;
    __syncthreads();

    // block top-64 in wave 0, publish to partner slot
    ull* slot_my = pay + (((size_t)pair * NITERS + it) * 2 + parity) * 64;
    ull* slot_pt = pay + (((size_t)pair * NITERS + it) * 2 + (parity ^ 1)) * 64;
    int* flag_my = flags + (((size_t)pair * NITERS + it) * 2 + parity);
    int* flag_pt = flags + (((size_t)pair * NITERS + it) * 2 + (parity ^ 1));

    if (wid == 0) {
      ull m0 = wmerge(wavetop[0][lane], wavetop[1][lane], lane);
      ull m1 = wmerge(wavetop[2][lane], wavetop[3][lane], lane);
      ull m2 = wmerge(wavetop[4][lane], wavetop[5][lane], lane);
      ull m3 = wmerge(wavetop[6][lane], wavetop[7][lane], lane);
      ull t0 = wmerge(m0, m1, lane);
      ull t1 = wmerge(m2, m3, lane);
      ull mytop = wmerge(t0, t1, lane);
      wavetop[0][lane] = mytop;                 // keep for local merge
      slot_my[lane] = mytop;                    // publish
      __threadfence();                          // release (device scope)
    }
    __syncthreads();
    if (tid == 0) {
      atomicExch(flag_my, 1);
      while (atomicCAS(flag_pt, 1, 1) == 0) __builtin_amdgcn_s_sleep(8);
    }
    __syncthreads();

    if (wid == 0) {
      __threadfence();                          // acquire (per reading lane)
      ull ptop = slot_pt[lane];
      ull t2 = wmerge(wavetop[0][lane], ptop, lane);
      ull old = beamkey[lane];
      ull nb = wmerge(old, t2, lane);           // all keys distinct
      ull same = __ballot(nb == old);
      beamkey[lane] = nb;
      beam_id[lane] = (int)(nb & 0xFFFFFFFFull);
      if (lane == 0) stop = (same == ~0ull) ? 1 : 0;
    }
    __syncthreads();
    if (stop) break;                            // identical in both blocks
  }

  if (parity == 0) final_topk(storage, qf, beam_id, dfull, out, b, B, lane, wid);
}

// ---------------- solo fallback (exact round-3 structure) ----------------

__global__ __launch_bounds__(NTH) void search_solo(
    const float* __restrict__ query, const float* __restrict__ VT,
    const float* __restrict__ storage, const int* __restrict__ neighbors,
    const int* __restrict__ entry_ids, float* __restrict__ out)
{
  __shared__ int   htab[HASHCAP];
  __shared__ ull   newkeys[MAXNEW];
  __shared__ ull   wavetop[NWAVE + 4][64];
  __shared__ ull   beamkey[EFS];
  __shared__ int   beam_id[EFS];
  __shared__ float qf[DM];
  __shared__ float qloc[DM];
  __shared__ float qn_s;
  __shared__ int   nc;
  __shared__ float dfull[EFS];

  const int b    = blockIdx.x;
  const int B    = gridDim.x;
  const int tid  = threadIdx.x;
  const int lane = tid & 63;
  const int wid  = tid >> 6;

  const ull FILLKEY = ((ull)fkey_enc(BIGF) << 32) | (unsigned)N_PTS;

  for (int i = tid; i < HASHCAP; i += NTH) htab[i] = -1;

  compute_qf(query, VT, qloc, qf, &qn_s, b, tid);
  const float qn = qn_s;

  if (wid == 0) {
    ull ek = PADKEY;
    if (lane < ENT) {
      int id = entry_ids[lane];
      if (visit_claim(htab, id)) {
        float d = dist_p(storage, qf, qn, id);
        ek = ((ull)fkey_enc(d) << 32) | (unsigned)id;
      }
    }
    ek = wsort64(ek, lane);
    if (ek == PADKEY) ek = FILLKEY;
    beamkey[lane] = ek;
    beam_id[lane] = (int)(ek & 0xFFFFFFFFull);
  }
  __syncthreads();

  for (int it = 0; it < NITERS; ++it) {
    ull kmax = beamkey[EFS - 1];
    if (tid == 0) nc = 0;
    __syncthreads();

    for (int ci = tid; ci < EFS * RNB; ci += NTH) {
      int e = ci >> 5;
      int r = ci & 31;
      int bid = beam_id[e];
      if (bid >= N_PTS) continue;
      int cid = neighbors[(size_t)bid * RNB + r];
      if (!visit_claim(htab, cid)) continue;
      float d = dist_p(storage, qf, qn, cid);
      ull key = ((ull)fkey_enc(d) << 32) | (unsigned)cid;
      if (key < kmax) {
        int p = atomicAdd(&nc, 1);
        newkeys[p] = key;
      }
    }
    __syncthreads();

    int cnt = nc;
    if (cnt == 0) break;

    ull t = PADKEY;
    int nchunks = (cnt + 63) >> 6;
    for (int c = wid; c < nchunks; c += NWAVE) {
      int idx = (c << 6) + lane;
      ull v = (idx < cnt) ? newkeys[idx] : PADKEY;
      v = wsort64(v, lane);
      t = wmerge(t, v, lane);
    }
    wavetop[wid][lane] = t;
    __syncthreads();

    if (wid < 4) {
      ull a = wavetop[2 * wid][lane];
      ull bb = wavetop[2 * wid + 1][lane];
      wavetop[NWAVE + wid][lane] = wmerge(a, bb, lane);
    }
    __syncthreads();
    if (wid == 0) {
      ull m0 = wmerge(wavetop[NWAVE + 0][lane], wavetop[NWAVE + 1][lane], lane);
      ull m1 = wmerge(wavetop[NWAVE + 2][lane], wavetop[NWAVE + 3][lane], lane);
      ull t2 = wmerge(m0, m1, lane);
      ull nb = wmerge(beamkey[lane], t2, lane);
      beamkey[lane] = nb;
      beam_id[lane] = (int)(nb & 0xFFFFFFFFull);
    }
    __syncthreads();
  }

  final_topk(storage, qf, beam_id, dfull, out, b, B, lane, wid);
}

extern "C" void kernel_launch(void* const* d_in, const int* in_sizes, int n_in,
                              void* d_out, int out_size, void* d_ws, size_t ws_size,
                              hipStream_t stream) {
  const float* query     = (const float*)d_in[0];
  const float* VT        = (const float*)d_in[1];
  const float* storage   = (const float*)d_in[2];
  const int*   neighbors = (const int*)d_in[3];
  const int*   entry_ids = (const int*)d_in[4];
  float* out = (float*)d_out;

  int B = in_sizes[0] / DM;  // 128

  size_t pay_bytes  = (size_t)B * NITERS * 2 * 64 * sizeof(ull);
  size_t flag_bytes = (size_t)B * NITERS * 2 * sizeof(int);

  if (ws_size >= pay_bytes + flag_bytes) {
    ull* pay   = (ull*)d_ws;
    int* flags = (int*)((char*)d_ws + pay_bytes);
    hipMemsetAsync(flags, 0, flag_bytes, stream);
    void* args[] = {(void*)&query, (void*)&VT, (void*)&storage, (void*)&neighbors,
                    (void*)&entry_ids, (void*)&out, (void*)&pay, (void*)&flags,
                    (void*)&B};
    hipError_t e = hipLaunchCooperativeKernel((const void*)search_pair,
                                              dim3(2 * B), dim3(NTH),
                                              args, 0, stream);
    if (e == hipSuccess) return;
  }
  search_solo<<<B, NTH, 0, stream>>>(query, VT, storage, neighbors, entry_ids, out);
}

// Round 6
// 146.746 us; speedup vs baseline: 1.1691x; 1.1691x over previous
//
#include <hip/hip_runtime.h>

typedef unsigned long long ull;

#define N_PTS   1000000
#define DM      128
#define DP      64
#define RNB     32
#define ENT     32
#define EFS     64
#define KOUT    10
#define NITERS  8
#define NTH     512
#define NWAVE   (NTH / 64)
#define HASHCAP 32768
#define MAXNEW  2112
#define BIGF    1e30f
#define PADKEY  0xFFFFFFFFFFFFFFFFull

__device__ __forceinline__ unsigned fkey_enc(float d) {
  unsigned b = __float_as_uint(d);
  return (b & 0x80000000u) ? ~b : (b | 0x80000000u);
}

// Scalar principal-distance (entry stage only; order bit-identical to R0-R5).
__device__ __forceinline__ float dist_p(const float* __restrict__ storage,
                                        const float* qf, float qn, int id) {
  int c = id < 0 ? 0 : (id > N_PTS - 1 ? N_PTS - 1 : id);
  const float4* row = (const float4*)(storage + (size_t)c * DM);
  float sq = 0.f, dt = 0.f;
#pragma unroll
  for (int j = 0; j < DP / 4; ++j) {
    float4 s = row[j];
    sq = fmaf(s.x, s.x, sq); sq = fmaf(s.y, s.y, sq);
    sq = fmaf(s.z, s.z, sq); sq = fmaf(s.w, s.w, sq);
    dt = fmaf(s.x, qf[4*j+0], dt); dt = fmaf(s.y, qf[4*j+1], dt);
    dt = fmaf(s.z, qf[4*j+2], dt); dt = fmaf(s.w, qf[4*j+3], dt);
  }
  float d = sq - 2.f * dt + qn;
  return (id >= N_PTS) ? BIGF : d;
}

__device__ __forceinline__ bool visit_claim(int* htab, int id) {
  unsigned h = ((unsigned)id * 2654435761u) & (HASHCAP - 1);
  while (true) {
    int cur = htab[h];
    if (cur == id) return false;
    if (cur == -1) {
      int old = atomicCAS(&htab[h], -1, id);
      if (old == -1) return true;
      if (old == id) return false;
    }
    h = (h + 1) & (HASHCAP - 1);
  }
}

__device__ __forceinline__ ull wsort64(ull key, int lane) {
#pragma unroll
  for (int k = 2; k <= 64; k <<= 1) {
#pragma unroll
    for (int j = k >> 1; j > 0; j >>= 1) {
      ull other = __shfl_xor(key, j);
      bool up = ((lane & k) == 0);
      bool lower = ((lane & j) == 0);
      ull mn = key < other ? key : other;
      ull mx = key < other ? other : key;
      key = (up == lower) ? mn : mx;
    }
  }
  return key;
}

__device__ __forceinline__ ull wbmerge64(ull key, int lane) {
#pragma unroll
  for (int j = 32; j > 0; j >>= 1) {
    ull other = __shfl_xor(key, j);
    bool lower = ((lane & j) == 0);
    ull mn = key < other ? key : other;
    ull mx = key < other ? other : key;
    key = lower ? mn : mx;
  }
  return key;
}

__device__ __forceinline__ ull wmerge(ull a, ull b, int lane) {
  ull brev = __shfl_xor(b, 63);
  ull c = a < brev ? a : brev;
  return wbmerge64(c, lane);
}

// Wave-aggregated LDS append: one atomic per wave. Returns slot (valid lanes).
__device__ __forceinline__ int wave_append(int* counter, bool want, int lane) {
  ull mask = __ballot(want);
  int pos = -1;
  if (mask) {
    int leader = __ffsll((long long)mask) - 1;
    int base = 0;
    if (lane == leader) base = atomicAdd(counter, (int)__popcll(mask));
    base = __shfl(base, leader);
    pos = base + (int)__popcll(mask & ((1ull << lane) - 1ull));
  }
  return pos;
}

__global__ __launch_bounds__(NTH) void search_kernel(
    const float* __restrict__ query,     // B x 128
    const float* __restrict__ VT,        // 128 x 128
    const float* __restrict__ storage,   // N x 128
    const int*   __restrict__ neighbors, // N x 32
    const int*   __restrict__ entry_ids, // 32
    float* __restrict__ out)             // [B*K ids | B*K dists] as float32
{
  __shared__ int   htab[HASHCAP];        // 128 KB
  __shared__ ull   newkeys[MAXNEW];      // 16.5 KB
  __shared__ ull   scratch[1024];        // 8 KB: evalids (phases) | wavetop (merge)
  __shared__ ull   beamkey[EFS];
  __shared__ int   beam_id[EFS];
  __shared__ __align__(16) float qf[DM];
  __shared__ float qloc[DM];
  __shared__ float qn_s;
  __shared__ int   nclaim, nc;
  __shared__ float dfull[EFS];

  int* evalids = (int*)scratch;          // capacity 2048 ids

  const int b    = blockIdx.x;
  const int B    = gridDim.x;
  const int tid  = threadIdx.x;
  const int lane = tid & 63;
  const int wid  = tid >> 6;
  const int grp  = lane >> 4;            // 0..3  candidate-slot within wave
  const int sub  = lane & 15;            // 0..15 16B-chunk within row

  const ull FILLKEY = ((ull)fkey_enc(BIGF) << 32) | (unsigned)N_PTS;

  for (int i = tid; i < HASHCAP; i += NTH) htab[i] = -1;

  // ---- q_full = query[b] @ VT.T ----
  if (tid < DM) qloc[tid] = query[(size_t)b * DM + tid];
  __syncthreads();
  if (tid < DM) {
    const float* vrow = VT + (size_t)tid * DM;
    float acc = 0.f;
#pragma unroll 8
    for (int d = 0; d < DM; ++d) acc = fmaf(qloc[d], vrow[d], acc);
    qf[tid] = acc;
  }
  __syncthreads();
  if (tid == 0) {
    float acc = 0.f;
    for (int d = 0; d < DP; ++d) acc = fmaf(qf[d], qf[d], acc);
    qn_s = acc;
  }
  __syncthreads();
  const float qn = qn_s;

  // my 16-float chunk of q_p (constant all iterations)
  const float4 mq = ((const float4*)qf)[sub];

  // ---- entry stage: wave 0, scalar path ----
  if (wid == 0) {
    ull ek = PADKEY;
    if (lane < ENT) {
      int id = entry_ids[lane];
      if (visit_claim(htab, id)) {
        float d = dist_p(storage, qf, qn, id);
        ek = ((ull)fkey_enc(d) << 32) | (unsigned)id;
      }
    }
    ek = wsort64(ek, lane);
    if (ek == PADKEY) ek = FILLKEY;
    beamkey[lane] = ek;
    beam_id[lane] = (int)(ek & 0xFFFFFFFFull);
  }
  __syncthreads();

  // ---- search iterations ----
  for (int it = 0; it < NITERS; ++it) {
    ull kmax = beamkey[EFS - 1];
    if (tid == 0) { nclaim = 0; nc = 0; }
    __syncthreads();

    // phase 1: propose + claim (no row gathers)
#pragma unroll
    for (int ci = tid; ci < EFS * RNB; ci += NTH) {
      int e = ci >> 5;
      int r = ci & 31;
      int bid = beam_id[e];
      bool want = false;
      int cid = 0;
      if (bid < N_PTS) {
        cid = neighbors[(size_t)bid * RNB + r];
        want = visit_claim(htab, cid);
      }
      int pos = wave_append(&nclaim, want, lane);
      if (want) evalids[pos] = cid;
    }
    __syncthreads();

    // phase 2: cooperative gather, 16 lanes per candidate, 16 cands/wave/trip
    int ne = nclaim;
    for (int base = wid * 16; base < ne; base += NWAVE * 16) {
      float4 s[4];
      int cid[4];
#pragma unroll
      for (int u = 0; u < 4; ++u) {
        int idx = base + u * 4 + grp;
        cid[u] = (idx < ne) ? evalids[idx] : 0;
        const float4* row = (const float4*)(storage + (size_t)cid[u] * DM);
        s[u] = row[sub];                      // 4 rows/instr, 8 lines/instr
      }
#pragma unroll
      for (int u = 0; u < 4; ++u) {
        int idx = base + u * 4 + grp;
        float4 v = s[u];
        float psq = 0.f, pdt = 0.f;
        psq = fmaf(v.x, v.x, psq); psq = fmaf(v.y, v.y, psq);
        psq = fmaf(v.z, v.z, psq); psq = fmaf(v.w, v.w, psq);
        pdt = fmaf(v.x, mq.x, pdt); pdt = fmaf(v.y, mq.y, pdt);
        pdt = fmaf(v.z, mq.z, pdt); pdt = fmaf(v.w, mq.w, pdt);
#pragma unroll
        for (int j = 1; j < 16; j <<= 1) {
          psq += __shfl_xor(psq, j);
          pdt += __shfl_xor(pdt, j);
        }
        float d = psq - 2.f * pdt + qn;
        ull key = ((ull)fkey_enc(d) << 32) | (unsigned)cid[u];
        bool pass = (sub == 0) && (idx < ne) && (key < kmax);
        int pos = wave_append(&nc, pass, lane);
        if (pass) newkeys[pos] = key;
      }
    }
    __syncthreads();

    int cnt = nc;
    if (cnt == 0) break;                     // beam fixed: exact early exit

    // per-wave top-64 (registers + shuffles); scratch becomes wavetop
    ull tk = PADKEY;
    int nchunks = (cnt + 63) >> 6;
    for (int c = wid; c < nchunks; c += NWAVE) {
      int idx = (c << 6) + lane;
      ull v = (idx < cnt) ? newkeys[idx] : PADKEY;
      v = wsort64(v, lane);
      tk = wmerge(tk, v, lane);
    }
    __syncthreads();                         // evalids dead
    scratch[wid * 64 + lane] = tk;
    __syncthreads();

    // tree merge: 8 -> 4 -> wave 0 merges 4 + beam
    if (wid < 4) {
      ull a  = scratch[(2 * wid) * 64 + lane];
      ull bb = scratch[(2 * wid + 1) * 64 + lane];
      scratch[(NWAVE + wid) * 64 + lane] = wmerge(a, bb, lane);
    }
    __syncthreads();
    if (wid == 0) {
      ull m0 = wmerge(scratch[(NWAVE + 0) * 64 + lane], scratch[(NWAVE + 1) * 64 + lane], lane);
      ull m1 = wmerge(scratch[(NWAVE + 2) * 64 + lane], scratch[(NWAVE + 3) * 64 + lane], lane);
      ull t2 = wmerge(m0, m1, lane);
      ull nb = wmerge(beamkey[lane], t2, lane);   // all keys distinct
      beamkey[lane] = nb;
      beam_id[lane] = (int)(nb & 0xFFFFFFFFull);
    }
    __syncthreads();
  }

  // ---- final: full 128-dim distances + top-k, wave 0 (order as R0-R5) ----
  if (wid == 0) {
    int id = beam_id[lane];
    int c = id < 0 ? 0 : (id > N_PTS - 1 ? N_PTS - 1 : id);
    const float4* row = (const float4*)(storage + (size_t)c * DM);
    float acc = 0.f;
#pragma unroll
    for (int j = 0; j < DM / 4; ++j) {
      float4 s = row[j];
      float dx = s.x - qf[4*j+0]; acc = fmaf(dx, dx, acc);
      dx = s.y - qf[4*j+1]; acc = fmaf(dx, dx, acc);
      dx = s.z - qf[4*j+2]; acc = fmaf(dx, dx, acc);
      dx = s.w - qf[4*j+3]; acc = fmaf(dx, dx, acc);
    }
    float dv = (id >= N_PTS) ? BIGF : acc;
    dfull[lane] = dv;
    ull fk = ((ull)fkey_enc(dv) << 32) | (unsigned)lane;
    fk = wsort64(fk, lane);
    if (lane < KOUT) {
      int pos = (int)(fk & 0xFFFFFFFFull);
      out[(size_t)b * KOUT + lane] = (float)beam_id[pos];
      out[(size_t)B * KOUT + (size_t)b * KOUT + lane] = dfull[pos];
    }
  }
}

extern "C" void kernel_launch(void* const* d_in, const int* in_sizes, int n_in,
                              void* d_out, int out_size, void* d_ws, size_t ws_size,
                              hipStream_t stream) {
  const float* query     = (const float*)d_in[0];
  const float* VT        = (const float*)d_in[1];
  const float* storage   = (const float*)d_in[2];
  const int*   neighbors = (const int*)d_in[3];
  const int*   entry_ids = (const int*)d_in[4];
  float* out = (float*)d_out;

  int B = in_sizes[0] / DM;  // 128
  search_kernel<<<B, NTH, 0, stream>>>(query, VT, storage, neighbors, entry_ids, out);
}

// Round 7
// 138.580 us; speedup vs baseline: 1.2380x; 1.0589x over previous
//
#include <hip/hip_runtime.h>

typedef unsigned long long ull;

#define N_PTS   1000000
#define DM      128
#define DP      64
#define RNB     32
#define ENT     32
#define EFS     64
#define KOUT    10
#define NITERS  8
#define NTH     1024
#define NWAVE   (NTH / 64)
#define HASHCAP 32768
#define MAXNEW  2048
#define BIGF    1e30f
#define PADKEY  0xFFFFFFFFFFFFFFFFull

__device__ __forceinline__ unsigned fkey_enc(float d) {
  unsigned b = __float_as_uint(d);
  return (b & 0x80000000u) ? ~b : (b | 0x80000000u);
}

// Principal-subspace distance. Fixed accumulation order; BIT-IDENTICAL to
// rounds 0-6 (absmax was 0.0 every round). Do not perturb.
__device__ __forceinline__ float dist_p(const float* __restrict__ storage,
                                        const float* qf, float qn, int id) {
  int c = id < 0 ? 0 : (id > N_PTS - 1 ? N_PTS - 1 : id);
  const float4* row = (const float4*)(storage + (size_t)c * DM);
  float sq = 0.f, dt = 0.f;
#pragma unroll
  for (int j = 0; j < DP / 4; ++j) {
    float4 s = row[j];
    sq = fmaf(s.x, s.x, sq); sq = fmaf(s.y, s.y, sq);
    sq = fmaf(s.z, s.z, sq); sq = fmaf(s.w, s.w, sq);
    dt = fmaf(s.x, qf[4*j+0], dt); dt = fmaf(s.y, qf[4*j+1], dt);
    dt = fmaf(s.z, qf[4*j+2], dt); dt = fmaf(s.w, qf[4*j+3], dt);
  }
  float d = sq - 2.f * dt + qn;
  return (id >= N_PTS) ? BIGF : d;
}

__device__ __forceinline__ bool visit_claim(int* htab, int id) {
  unsigned h = ((unsigned)id * 2654435761u) & (HASHCAP - 1);
  while (true) {
    int cur = htab[h];
    if (cur == id) return false;
    if (cur == -1) {
      int old = atomicCAS(&htab[h], -1, id);
      if (old == -1) return true;
      if (old == id) return false;
    }
    h = (h + 1) & (HASHCAP - 1);
  }
}

__device__ __forceinline__ ull wsort64(ull key, int lane) {
#pragma unroll
  for (int k = 2; k <= 64; k <<= 1) {
#pragma unroll
    for (int j = k >> 1; j > 0; j >>= 1) {
      ull other = __shfl_xor(key, j);
      bool up = ((lane & k) == 0);
      bool lower = ((lane & j) == 0);
      ull mn = key < other ? key : other;
      ull mx = key < other ? other : key;
      key = (up == lower) ? mn : mx;
    }
  }
  return key;
}

__device__ __forceinline__ ull wbmerge64(ull key, int lane) {
#pragma unroll
  for (int j = 32; j > 0; j >>= 1) {
    ull other = __shfl_xor(key, j);
    bool lower = ((lane & j) == 0);
    ull mn = key < other ? key : other;
    ull mx = key < other ? other : key;
    key = lower ? mn : mx;
  }
  return key;
}

__device__ __forceinline__ ull wmerge(ull a, ull b, int lane) {
  ull brev = __shfl_xor(b, 63);
  ull c = a < brev ? a : brev;
  return wbmerge64(c, lane);
}

__global__ __launch_bounds__(NTH) void search_kernel(
    const float* __restrict__ query,     // B x 128
    const float* __restrict__ VT,        // 128 x 128
    const float* __restrict__ storage,   // N x 128
    const int*   __restrict__ neighbors, // N x 32
    const int*   __restrict__ entry_ids, // 32
    float* __restrict__ out)             // [B*K ids | B*K dists] as float32
{
  __shared__ int   htab[HASHCAP];        // 128 KB
  __shared__ ull   newkeys[MAXNEW];      // 16 KB
  __shared__ ull   wavetop[NWAVE][64];   // 8 KB
  __shared__ ull   beamkey[EFS];
  __shared__ int   beam_id[EFS];
  __shared__ float qf[DM];
  __shared__ float qloc[DM];
  __shared__ float qn_s;
  __shared__ int   nc;
  __shared__ float dfull[EFS];

  const int b    = blockIdx.x;
  const int B    = gridDim.x;
  const int tid  = threadIdx.x;
  const int lane = tid & 63;
  const int wid  = tid >> 6;

  const ull FILLKEY = ((ull)fkey_enc(BIGF) << 32) | (unsigned)N_PTS;

  for (int i = tid; i < HASHCAP; i += NTH) htab[i] = -1;

  // ---- q_full = query[b] @ VT.T ----
  if (tid < DM) qloc[tid] = query[(size_t)b * DM + tid];
  __syncthreads();
  if (tid < DM) {
    const float* vrow = VT + (size_t)tid * DM;
    float acc = 0.f;
#pragma unroll 8
    for (int d = 0; d < DM; ++d) acc = fmaf(qloc[d], vrow[d], acc);
    qf[tid] = acc;
  }
  __syncthreads();
  if (tid == 0) {
    float acc = 0.f;
    for (int d = 0; d < DP; ++d) acc = fmaf(qf[d], qf[d], acc);
    qn_s = acc;
  }
  __syncthreads();
  const float qn = qn_s;

  // ---- entry stage: wave 0 ----
  if (wid == 0) {
    ull ek = PADKEY;
    if (lane < ENT) {
      int id = entry_ids[lane];
      if (visit_claim(htab, id)) {
        float d = dist_p(storage, qf, qn, id);
        ek = ((ull)fkey_enc(d) << 32) | (unsigned)id;
      }
    }
    ek = wsort64(ek, lane);
    if (ek == PADKEY) ek = FILLKEY;
    beamkey[lane] = ek;
    beam_id[lane] = (int)(ek & 0xFFFFFFFFull);
  }
  __syncthreads();

  // ---- search iterations ----
  for (int it = 0; it < NITERS; ++it) {
    ull kmax = beamkey[EFS - 1];
    if (tid == 0) nc = 0;
    __syncthreads();

    // fused propose + claim + eval, 2 trips/thread, neighbor ids prefetched
    {
      const int ci0 = tid;            // trip 0: e = tid>>5, r = tid&31
      const int ci1 = tid + NTH;      // trip 1
      int bid0 = beam_id[ci0 >> 5];
      int bid1 = beam_id[ci1 >> 5];
      // issue both neighbor loads before any claim (overlap their latency)
      int cid0 = (bid0 < N_PTS) ? neighbors[(size_t)bid0 * RNB + (ci0 & 31)] : N_PTS;
      int cid1 = (bid1 < N_PTS) ? neighbors[(size_t)bid1 * RNB + (ci1 & 31)] : N_PTS;

      bool w0 = (cid0 < N_PTS) && visit_claim(htab, cid0);
      if (w0) {
        float d = dist_p(storage, qf, qn, cid0);
        ull key = ((ull)fkey_enc(d) << 32) | (unsigned)cid0;
        if (key < kmax) { int p = atomicAdd(&nc, 1); newkeys[p] = key; }
      }
      bool w1 = (cid1 < N_PTS) && visit_claim(htab, cid1);
      if (w1) {
        float d = dist_p(storage, qf, qn, cid1);
        ull key = ((ull)fkey_enc(d) << 32) | (unsigned)cid1;
        if (key < kmax) { int p = atomicAdd(&nc, 1); newkeys[p] = key; }
      }
    }
    __syncthreads();

    int cnt = nc;
    if (cnt == 0) break;                     // beam fixed: exact early exit

    // per-wave top-64 over candidate chunks (registers + shuffles only)
    ull tk = PADKEY;
    int nchunks = (cnt + 63) >> 6;
    for (int c = wid; c < nchunks; c += NWAVE) {
      int idx = (c << 6) + lane;
      ull v = (idx < cnt) ? newkeys[idx] : PADKEY;
      v = wsort64(v, lane);
      tk = wmerge(tk, v, lane);
    }
    wavetop[wid][lane] = tk;
    __syncthreads();

    // wave 0 sequentially merges 16 wavetops + beam (no extra barriers)
    if (wid == 0) {
      ull acc = wavetop[0][lane];
#pragma unroll
      for (int w = 1; w < NWAVE; ++w) acc = wmerge(acc, wavetop[w][lane], lane);
      ull nb = wmerge(beamkey[lane], acc, lane);   // all keys distinct
      beamkey[lane] = nb;
      beam_id[lane] = (int)(nb & 0xFFFFFFFFull);
    }
    __syncthreads();
  }

  // ---- final: full 128-dim distances + top-k, wave 0 (order as R0-R6) ----
  if (wid == 0) {
    int id = beam_id[lane];
    int c = id < 0 ? 0 : (id > N_PTS - 1 ? N_PTS - 1 : id);
    const float4* row = (const float4*)(storage + (size_t)c * DM);
    float acc = 0.f;
#pragma unroll
    for (int j = 0; j < DM / 4; ++j) {
      float4 s = row[j];
      float dx = s.x - qf[4*j+0]; acc = fmaf(dx, dx, acc);
      dx = s.y - qf[4*j+1]; acc = fmaf(dx, dx, acc);
      dx = s.z - qf[4*j+2]; acc = fmaf(dx, dx, acc);
      dx = s.w - qf[4*j+3]; acc = fmaf(dx, dx, acc);
    }
    float dv = (id >= N_PTS) ? BIGF : acc;
    dfull[lane] = dv;
    ull fk = ((ull)fkey_enc(dv) << 32) | (unsigned)lane;
    fk = wsort64(fk, lane);
    if (lane < KOUT) {
      int pos = (int)(fk & 0xFFFFFFFFull);
      out[(size_t)b * KOUT + lane] = (float)beam_id[pos];
      out[(size_t)B * KOUT + (size_t)b * KOUT + lane] = dfull[pos];
    }
  }
}

extern "C" void kernel_launch(void* const* d_in, const int* in_sizes, int n_in,
                              void* d_out, int out_size, void* d_ws, size_t ws_size,
                              hipStream_t stream) {
  const float* query     = (const float*)d_in[0];
  const float* VT        = (const float*)d_in[1];
  const float* storage   = (const float*)d_in[2];
  const int*   neighbors = (const int*)d_in[3];
  const int*   entry_ids = (const int*)d_in[4];
  float* out = (float*)d_out;

  int B = in_sizes[0] / DM;  // 128
  search_kernel<<<B, NTH, 0, stream>>>(query, VT, storage, neighbors, entry_ids, out);
}